// Round 15
// baseline (17773.886 us; speedup 1.0000x reference)
//
#include <hip/hip_runtime.h>
#include <hip/hip_bf16.h>
#include <hip/hip_fp16.h>

#define NEGV (-1e30f)

constexpr int Bc = 64;     // batch == one block per lane
constexpr int Dc = 2048;   // pdf dim
constexpr int Tc = 150;    // time steps
constexpr int Sc = 20000;  // states (compile-time for LDS sizing)
constexpr int NTHR = 1024; // threads per lane-block
constexpr int ELL_ROWS = 384;  // max arcs per thread column (mean 256, sigma~16)
// exp-domain re-centering (proven R12): per-step rescale by e^{5}/max(EA[0..3]).
constexpr float EXP_NEG_DRIFT = 148.41316f;   // e^{5}
constexpr float STORE_CAP = 60000.0f;
constexpr float OFF_INIT = -10.0f;

// ---- elementwise: E = fp16(exp(logp)), same [T][B][D] layout (no transpose) ----
__global__ void expcvt_kernel(const float* __restrict__ in, __half* __restrict__ out,
                              size_t n) {
    size_t i = (size_t)blockIdx.x * blockDim.x + threadIdx.x;
    size_t stride = (size_t)gridDim.x * blockDim.x;
    for (; i < n; i += stride) out[i] = __float2half(__expf(in[i]));
}

// ---- histogram of to_state ----
__global__ void hist_kernel(const int* __restrict__ to, int* __restrict__ count, int A) {
    int i = blockIdx.x * blockDim.x + threadIdx.x;
    if (i < A) atomicAdd(&count[to[i]], 1);
}

// ---- single-block exclusive scan -> row_ptr, cursor ----
__global__ void scan_kernel(const int* __restrict__ count, int* __restrict__ row_ptr,
                            int* __restrict__ cursor, int S) {
    __shared__ int lds[1024];
    const int tid = threadIdx.x;
    const int n = 1024;
    const int chunk = (S + n - 1) / n;
    const int lo = tid * chunk;
    const int hi = min(lo + chunk, S);
    int local = 0;
    for (int j = lo; j < hi; ++j) local += count[j];
    lds[tid] = local;
    __syncthreads();
    for (int off = 1; off < 1024; off <<= 1) {
        int add = (tid >= off) ? lds[tid - off] : 0;
        __syncthreads();
        lds[tid] += add;
        __syncthreads();
    }
    int excl = (tid > 0) ? lds[tid - 1] : 0;
    for (int j = lo; j < hi; ++j) {
        int c = count[j];
        row_ptr[j] = excl;
        cursor[j]  = excl;
        excl += c;
    }
    if (tid == n - 1) row_ptr[S] = lds[n - 1];
}

// ---- per-state -> (thread column, thread CSR base) map for ELL scatter ----
__global__ void colmap_kernel(const int* __restrict__ rp, int* __restrict__ sbase,
                              unsigned short* __restrict__ kcol, int S) {
    int st = blockIdx.x * blockDim.x + threadIdx.x;
    if (st >= S) return;
    int k  = (int)(((long long)st * NTHR) / S);      // owning thread column
    int lo = (int)(((long long)k * S) / NTHR);       // its first state
    kcol[st]  = (unsigned short)k;
    sbase[st] = rp[lo];                              // its CSR base
}

// ---- scatter arcs directly into ELL [slot][1024]: {from u32, pdf u16|exp(w) fp16} ----
__global__ void scatter_ell_kernel(const int* __restrict__ to, const int* __restrict__ from,
                                   const int* __restrict__ pdf, const float* __restrict__ w,
                                   int* __restrict__ cursor, const int* __restrict__ sbase,
                                   const unsigned short* __restrict__ kcol,
                                   uint2* __restrict__ ell, int A) {
    int i = blockIdx.x * blockDim.x + threadIdx.x;
    if (i >= A) return;
    int st = to[i];
    int p = atomicAdd(&cursor[st], 1);     // global CSR position
    int j = p - sbase[st];                 // slot within owning thread's run
    if (j >= ELL_ROWS) return;             // safety guard (statistically never)
    unsigned short wb = __half_as_ushort(__float2half(__expf(w[i])));
    ell[(size_t)j * NTHR + kcol[st]] =
        make_uint2((unsigned)from[i],
                   ((unsigned)pdf[i] & 0xffffu) | ((unsigned)wb << 16));
}

// ---- the whole recursion: one block per batch lane, alpha ping-pong in LDS ----
__global__ __launch_bounds__(1024, 1)
void lane_kernel(const __half* __restrict__ Etab,      // [T][B][D] fp16 exp(logp)
                 const float* __restrict__ init_logp,
                 const int* __restrict__ rp,
                 const uint2* __restrict__ ell,
                 __half* __restrict__ alphaF,          // [B][S] final EA
                 float* __restrict__ offF,             // [B]
                 int T) {
    __shared__ __half lA[2][Sc];          // 80 KB ping-pong alpha (exp domain)
    __shared__ __half lE[Dc];             // 4 KB current E row
    __shared__ unsigned char lC[Sc];      // 20 KB per-state arc counts
    const int b = blockIdx.x;
    const int k = threadIdx.x;
    const int lo_s = (int)(((long long)k * Sc) / NTHR);
    const int hi_s = (int)(((long long)(k + 1) * Sc) / NTHR);

    for (int s = k; s < Sc; s += NTHR) {
        lA[0][s] = __float2half(fminf(__expf(init_logp[s] - OFF_INIT), STORE_CAP));
        int c = rp[s + 1] - rp[s];
        lC[s] = (unsigned char)(c > 255 ? 255 : c);
    }
    float offAcc = OFF_INIT;
    int cur = 0;
    __syncthreads();

    for (int t = 0; t < T; ++t) {
        const __half* Erow = Etab + ((size_t)t * Bc + b) * Dc;
        for (int d = k; d < Dc; d += NTHR) lE[d] = Erow[d];
        __syncthreads();                  // E staged; alpha[cur] stable

        const float r0 = __half2float(lA[cur][0]);
        const float r1 = __half2float(lA[cur][1]);
        const float r2 = __half2float(lA[cur][2]);
        const float r3 = __half2float(lA[cur][3]);
        float dref = fmaxf(fmaxf(fmaxf(r0, r1), fmaxf(r2, r3)), 1e-20f);
        const float scale = EXP_NEG_DRIFT / dref;

        const __half* __restrict__ Ac = lA[cur];
        __half* __restrict__ An = lA[cur ^ 1];
        int j = 0;
        for (int st = lo_s; st < hi_s; ++st) {
            const int n = lC[st];
            float acc = 0.0f;
            for (int a2 = 0; a2 < n; ++a2, ++j) {
                const uint2 R = ell[(size_t)j * NTHR + k];   // coalesced column read
                const float w  = __half2float(__ushort_as_half((unsigned short)(R.y >> 16)));
                const float e  = __half2float(lE[R.y & 0xffffu]);
                const float al = __half2float(Ac[R.x]);
                acc = fmaf(al * w, e, acc);
            }
            An[st] = __float2half(fminf(acc * scale, STORE_CAP));
        }
        if (k == 0) offAcc += (__logf(dref) - 5.0f);
        cur ^= 1;
        __syncthreads();                  // new alpha complete before next step
    }

    for (int s = k; s < Sc; s += NTHR)
        alphaF[(size_t)b * Sc + s] = lA[cur][s];
    if (k == 0) offF[b] = offAcc;
}

// ---- final: per-lane logsumexp over [B][S] rows + OFF[b], atomicAdd ----
__global__ void final_reduce_row(const __half* __restrict__ alphaF,
                                 const float* __restrict__ offF,
                                 const float* __restrict__ final_logp,
                                 float* __restrict__ out, int S) {
    const int b = blockIdx.x;
    const int tid = threadIdx.x;  // 256
    float m = NEGV, sum = 0.0f;
    for (int s = tid; s < S; s += 256) {
        float v = __logf(__half2float(alphaF[(size_t)b * S + s]) + 1e-35f) + final_logp[s];
        float nm = fmaxf(m, v);
        sum = sum * __expf(m - nm) + __expf(v - nm);
        m = nm;
    }
    __shared__ float mArr[256], sArr[256];
    mArr[tid] = m; sArr[tid] = sum;
    __syncthreads();
    for (int o = 128; o > 0; o >>= 1) {
        if (tid < o) {
            float m2 = mArr[tid + o], s2 = sArr[tid + o];
            float nm = fmaxf(mArr[tid], m2);
            sArr[tid] = sArr[tid] * __expf(mArr[tid] - nm) + s2 * __expf(m2 - nm);
            mArr[tid] = nm;
        }
        __syncthreads();
    }
    if (tid == 0) {
        float per = fmaxf(mArr[0], NEGV) + logf(sArr[0] + 1e-30f) + offF[b];
        atomicAdd(out, per);
    }
}

// ================= fallback path (generic shapes / small ws): R12-proven =================
__global__ void fb_init_alpha(const float* __restrict__ init_logp,
                              __half* __restrict__ alpha_h, float* __restrict__ off, int S) {
    int idx = blockIdx.x * blockDim.x + threadIdx.x;
    int wave = idx >> 6, lane = threadIdx.x & 63;
    if (wave < S)
        alpha_h[(size_t)wave * Bc + lane] =
            __float2half(fminf(__expf(init_logp[wave] - OFF_INIT), STORE_CAP));
    if (idx < Bc) off[idx] = OFF_INIT;
}

__global__ void fb_scatter(const int* __restrict__ to, const int* __restrict__ from,
                           const int* __restrict__ pdf, const float* __restrict__ w,
                           int* __restrict__ cursor, uint2* __restrict__ a_pack, int A) {
    int i = blockIdx.x * blockDim.x + threadIdx.x;
    if (i >= A) return;
    int t = to[i];
    int p = atomicAdd(&cursor[t], 1);
    unsigned short wb = __half_as_ushort(__float2half(__expf(w[i])));
    a_pack[p] = make_uint2((unsigned)from[i],
                           ((unsigned)pdf[i] & 0xffffu) | ((unsigned)wb << 16));
}

__global__ void fb_step(const __half* __restrict__ alpha_old, __half* __restrict__ alpha_new,
                        const float* __restrict__ off_old, float* __restrict__ off_new,
                        const float* __restrict__ logp_raw,   // [B][D] f32
                        const int* __restrict__ row_ptr, const uint2* __restrict__ arcs,
                        int S) {
    const int wave = (blockIdx.x * blockDim.x + threadIdx.x) >> 6;
    const int lane = threadIdx.x & 63;
    if (wave >= S) return;
    const int lo = __builtin_amdgcn_readfirstlane(row_ptr[wave]);
    const int hi = __builtin_amdgcn_readfirstlane(row_ptr[wave + 1]);
    const float r0 = __half2float(alpha_old[0 * Bc + lane]);
    const float r1 = __half2float(alpha_old[1 * Bc + lane]);
    const float r2 = __half2float(alpha_old[2 * Bc + lane]);
    const float r3 = __half2float(alpha_old[3 * Bc + lane]);
    float dref = fmaxf(fmaxf(fmaxf(r0, r1), fmaxf(r2, r3)), 1e-20f);
    const float scale = EXP_NEG_DRIFT / dref;
    float s0 = 0.0f;
    for (int i = lo; i < hi; ++i) {
        const uint2 A0 = arcs[i];
        const float w0 = __half2float(__ushort_as_half((unsigned short)(A0.y >> 16)));
        const float e0 = __expf(logp_raw[(size_t)lane * Dc + (A0.y & 0xffffu)]);
        s0 = fmaf(__half2float(alpha_old[(size_t)A0.x * Bc + lane]) * w0, e0, s0);
    }
    alpha_new[(size_t)wave * Bc + lane] = __float2half(fminf(s0 * scale, STORE_CAP));
    if (wave == 0) off_new[lane] = off_old[lane] + (__logf(dref) - 5.0f);
}

__global__ void fb_final(const __half* __restrict__ alpha, const float* __restrict__ off,
                         const float* __restrict__ final_logp, float* __restrict__ out,
                         int S) {
    const int b = blockIdx.x;
    const int tid = threadIdx.x;
    float m = NEGV, sum = 0.0f;
    for (int s = tid; s < S; s += 256) {
        float v = __logf(__half2float(alpha[(size_t)s * Bc + b]) + 1e-35f) + final_logp[s];
        float nm = fmaxf(m, v);
        sum = sum * __expf(m - nm) + __expf(v - nm);
        m = nm;
    }
    __shared__ float mArr[256], sArr[256];
    mArr[tid] = m; sArr[tid] = sum;
    __syncthreads();
    for (int o = 128; o > 0; o >>= 1) {
        if (tid < o) {
            float m2 = mArr[tid + o], s2 = sArr[tid + o];
            float nm = fmaxf(mArr[tid], m2);
            sArr[tid] = sArr[tid] * __expf(mArr[tid] - nm) + s2 * __expf(m2 - nm);
            mArr[tid] = nm;
        }
        __syncthreads();
    }
    if (tid == 0) {
        float per = fmaxf(mArr[0], NEGV) + logf(sArr[0] + 1e-30f) + off[b];
        atomicAdd(out, per);
    }
}

extern "C" void kernel_launch(void* const* d_in, const int* in_sizes, int n_in,
                              void* d_out, int out_size, void* d_ws, size_t ws_size,
                              hipStream_t stream) {
    const float* input      = (const float*)d_in[0];
    const float* arc_logw   = (const float*)d_in[1];
    const float* init_logp  = (const float*)d_in[2];
    const float* final_logp = (const float*)d_in[3];
    const int*   from_state = (const int*)d_in[4];
    const int*   to_state   = (const int*)d_in[5];
    const int*   pdf_id     = (const int*)d_in[6];
    const int S = in_sizes[2];
    const int A = in_sizes[4];

    char* ws = (char*)d_ws;
    size_t off = 0;
    auto alloc = [&](size_t bytes) -> char* {
        char* p = ws + off;
        off += (bytes + 255) & ~(size_t)255;
        return p;
    };

    const size_t etab_b  = (size_t)Tc * Bc * Dc * 2;            // 39.3 MB
    const size_t ell_b   = (size_t)ELL_ROWS * NTHR * 8;         // 3.15 MB
    const size_t main_need = etab_b + ell_b + (size_t)Bc * Sc * 2 +  // alphaF
                             3 * ((size_t)(S + 1) * 4) + (size_t)S * 6 + 8192;
    const bool shapes_ok = (S == Sc) && (in_sizes[0] == (int)((size_t)Tc * Bc * Dc));
    const bool do_main = shapes_ok && (ws_size >= main_need + (1 << 20));

    hipMemsetAsync(d_out, 0, sizeof(float), stream);

    if (do_main) {
        __half* Etab   = (__half*)alloc(etab_b);
        uint2*  ell    = (uint2*)alloc(ell_b);
        __half* alphaF = (__half*)alloc((size_t)Bc * Sc * 2);
        float*  offF   = (float*)alloc(Bc * 4);
        int* rp     = (int*)alloc((size_t)(S + 1) * 4);
        int* cursor = (int*)alloc((size_t)(S + 1) * 4);
        int* count  = (int*)alloc((size_t)(S + 1) * 4);
        int* sbase  = (int*)alloc((size_t)S * 4);
        unsigned short* kcol = (unsigned short*)alloc((size_t)S * 2);

        hipMemsetAsync(count, 0, (size_t)S * 4, stream);
        expcvt_kernel<<<2048, 256, 0, stream>>>(input, Etab, (size_t)Tc * Bc * Dc);
        hist_kernel<<<(A + 255) / 256, 256, 0, stream>>>(to_state, count, A);
        scan_kernel<<<1, 1024, 0, stream>>>(count, rp, cursor, S);
        colmap_kernel<<<(S + 255) / 256, 256, 0, stream>>>(rp, sbase, kcol, S);
        scatter_ell_kernel<<<(A + 255) / 256, 256, 0, stream>>>(
            to_state, from_state, pdf_id, arc_logw, cursor, sbase, kcol, ell, A);
        lane_kernel<<<Bc, NTHR, 0, stream>>>(Etab, init_logp, rp, ell, alphaF, offF, Tc);
        final_reduce_row<<<Bc, 256, 0, stream>>>(alphaF, offF, final_logp,
                                                 (float*)d_out, S);
    } else {
        __half* alphaA = (__half*)alloc((size_t)S * Bc * 2);
        __half* alphaB = (__half*)alloc((size_t)S * Bc * 2);
        float* offA    = (float*)alloc(Bc * 4);
        float* offB    = (float*)alloc(Bc * 4);
        int* rp     = (int*)alloc((size_t)(S + 1) * 4);
        int* cursor = (int*)alloc((size_t)(S + 1) * 4);
        int* count  = (int*)alloc((size_t)(S + 1) * 4);
        uint2* a_pack = (uint2*)alloc((size_t)A * 8);

        hipMemsetAsync(count, 0, (size_t)S * 4, stream);
        fb_init_alpha<<<(S * Bc + 255) / 256, 256, 0, stream>>>(init_logp, alphaA, offA, S);
        hist_kernel<<<(A + 255) / 256, 256, 0, stream>>>(to_state, count, A);
        scan_kernel<<<1, 1024, 0, stream>>>(count, rp, cursor, S);
        fb_scatter<<<(A + 255) / 256, 256, 0, stream>>>(to_state, from_state, pdf_id,
                                                        arc_logw, cursor, a_pack, A);
        __half* curA = alphaA; __half* nxtA = alphaB;
        float* curO = offA;    float* nxtO = offB;
        const int step_blocks = (S + 3) / 4;
        for (int t = 0; t < Tc; ++t) {
            fb_step<<<step_blocks, 256, 0, stream>>>(curA, nxtA, curO, nxtO,
                                                     input + (size_t)t * Bc * Dc,
                                                     rp, a_pack, S);
            __half* ta = curA; curA = nxtA; nxtA = ta;
            float* to_ = curO; curO = nxtO; nxtO = to_;
        }
        fb_final<<<Bc, 256, 0, stream>>>(curA, curO, final_logp, (float*)d_out, S);
    }
}

// Round 16
// 2018.160 us; speedup vs baseline: 8.8070x; 8.8070x over previous
//
#include <hip/hip_runtime.h>
#include <hip/hip_bf16.h>
#include <hip/hip_fp16.h>

#define NEGV (-1e30f)

constexpr int Bc = 64;    // batch == wave size
constexpr int Dc = 2048;  // pdf dim
constexpr int Tc = 150;   // time steps
// exp-domain re-centering: stored EA ~ O(1..100); per-step rescale by
// e^{+5}/max(EA[0..3]) counters the ~-5 nat/step drift (self-correcting).
constexpr float EXP_NEG_DRIFT = 148.41316f;   // e^{5}
constexpr float STORE_CAP = 60000.0f;         // fp16 max 65504, keep headroom
constexpr float OFF_INIT = -10.0f;            // stored_init = exp(init_logp + 10)

// ---- transpose input [T][B][D] f32 -> E=exp(logp) [T][D][B] fp16 ----
__global__ void transpose_kernel(const float* __restrict__ in, __half* __restrict__ out) {
    __shared__ float tile[64][65];
    const int t  = blockIdx.y;
    const int d0 = blockIdx.x * 64;
    const int lane = threadIdx.x & 63;
    const int w    = threadIdx.x >> 6;  // 0..3
    const float* inp = in + (size_t)t * Bc * Dc;
    #pragma unroll
    for (int b = w; b < 64; b += 4)
        tile[b][lane] = inp[(size_t)b * Dc + d0 + lane];
    __syncthreads();
    __half* outp = out + (size_t)t * Dc * Bc;
    #pragma unroll
    for (int d = w; d < 64; d += 4)
        outp[(size_t)(d0 + d) * Bc + lane] = __float2half(__expf(tile[lane][d]));
}

// ---- EA[s][b] = exp(init_logp[s] - OFF_INIT); off[b] = OFF_INIT ----
__global__ void init_alpha_kernel(const float* __restrict__ init_logp,
                                  __half* __restrict__ alpha_h,
                                  float* __restrict__ off, int S) {
    int idx  = blockIdx.x * blockDim.x + threadIdx.x;
    int wave = idx >> 6;
    int lane = threadIdx.x & 63;
    if (wave < S) {
        float v = __expf(init_logp[wave] - OFF_INIT);
        alpha_h[(size_t)wave * Bc + lane] = __float2half(fminf(v, STORE_CAP));
    }
    if (idx < Bc) off[idx] = OFF_INIT;
}

// ---- histogram of to_state ----
__global__ void hist_kernel(const int* __restrict__ to, int* __restrict__ count, int A) {
    int i = blockIdx.x * blockDim.x + threadIdx.x;
    if (i < A) atomicAdd(&count[to[i]], 1);
}

// ---- single-block exclusive scan -> row_ptr, cursor ----
__global__ void scan_kernel(const int* __restrict__ count, int* __restrict__ row_ptr,
                            int* __restrict__ cursor, int S) {
    __shared__ int lds[1024];
    const int tid = threadIdx.x;
    const int n = 1024;
    const int chunk = (S + n - 1) / n;
    const int lo = tid * chunk;
    const int hi = min(lo + chunk, S);
    int local = 0;
    for (int j = lo; j < hi; ++j) local += count[j];
    lds[tid] = local;
    __syncthreads();
    for (int off = 1; off < 1024; off <<= 1) {
        int add = (tid >= off) ? lds[tid - off] : 0;
        __syncthreads();
        lds[tid] += add;
        __syncthreads();
    }
    int excl = (tid > 0) ? lds[tid - 1] : 0;
    for (int j = lo; j < hi; ++j) {
        int c = count[j];
        row_ptr[j] = excl;
        cursor[j]  = excl;
        excl += c;
    }
    if (tid == n - 1) row_ptr[S] = lds[n - 1];
}

// ---- scatter arcs sorted by to_state, packed 8B: {f:u32, pdf:u16, exp(w):fp16} ----
__global__ void scatter_kernel(const int* __restrict__ to, const int* __restrict__ from,
                               const int* __restrict__ pdf, const float* __restrict__ w,
                               int* __restrict__ cursor, uint2* __restrict__ a_pack, int A) {
    int i = blockIdx.x * blockDim.x + threadIdx.x;
    if (i >= A) return;
    int t = to[i];
    int p = atomicAdd(&cursor[t], 1);
    unsigned short wb = __half_as_ushort(__float2half(__expf(w[i])));
    a_pack[p] = make_uint2((unsigned)from[i],
                           ((unsigned)pdf[i] & 0xffffu) | ((unsigned)wb << 16));
}

// ---- one forward step, EXP DOMAIN: s = sum EA[f]*ew*E[p]; no transcendentals ----
// wave = state, lane = batch. XCD-contiguous swizzle for L2 locality.
// TR: E is fp16 [D][B]. else: raw f32 logp [B][D] (fallback, exp inline).
template <bool TR>
__global__ void step_kernel(const __half* __restrict__ alpha_old,  // [S][B] EA fp16
                            __half* __restrict__ alpha_new,        // [S][B] EA fp16
                            const float* __restrict__ off_old,     // [B]
                            float* __restrict__ off_new,           // [B]
                            const void* __restrict__ logp_t,
                            const int* __restrict__ row_ptr,
                            const uint2* __restrict__ arcs, int S) {
    const int nb  = gridDim.x;
    const int cpx = nb >> 3;
    const int bid = blockIdx.x;
    const int swz = (nb % 8 == 0) ? ((bid & 7) * cpx + (bid >> 3)) : bid;
    const int wave = (swz * blockDim.x + threadIdx.x) >> 6;
    const int lane = threadIdx.x & 63;
    if (wave >= S) return;
    const int lo = __builtin_amdgcn_readfirstlane(row_ptr[wave]);
    const int hi = __builtin_amdgcn_readfirstlane(row_ptr[wave + 1]);
    const __half* lph = (const __half*)logp_t;
    const float*  lpf = (const float*)logp_t;

    // multiplicative re-center reference from states 0..3 (self-correcting)
    const float r0 = __half2float(alpha_old[0 * Bc + lane]);
    const float r1 = __half2float(alpha_old[1 * Bc + lane]);
    const float r2 = __half2float(alpha_old[2 * Bc + lane]);
    const float r3 = __half2float(alpha_old[3 * Bc + lane]);
    const float dref = fmaxf(fmaxf(fmaxf(r0, r1), fmaxf(r2, r3)), 1e-20f);
    const float scale = EXP_NEG_DRIFT / dref;   // = exp(-delta)

    float s0 = 0.0f, s1 = 0.0f, s2 = 0.0f, s3 = 0.0f;
    int i = lo;
    for (; i + 3 < hi; i += 4) {
        const uint2 A0 = arcs[i],     A1 = arcs[i + 1];
        const uint2 A2 = arcs[i + 2], A3 = arcs[i + 3];
        const float w0 = __half2float(__ushort_as_half((unsigned short)(A0.y >> 16)));
        const float w1 = __half2float(__ushort_as_half((unsigned short)(A1.y >> 16)));
        const float w2 = __half2float(__ushort_as_half((unsigned short)(A2.y >> 16)));
        const float w3 = __half2float(__ushort_as_half((unsigned short)(A3.y >> 16)));
        const float e0 = TR ? __half2float(lph[(size_t)(A0.y & 0xffffu) * Bc + lane])
                            : __expf(lpf[(size_t)lane * Dc + (A0.y & 0xffffu)]);
        const float e1 = TR ? __half2float(lph[(size_t)(A1.y & 0xffffu) * Bc + lane])
                            : __expf(lpf[(size_t)lane * Dc + (A1.y & 0xffffu)]);
        const float e2 = TR ? __half2float(lph[(size_t)(A2.y & 0xffffu) * Bc + lane])
                            : __expf(lpf[(size_t)lane * Dc + (A2.y & 0xffffu)]);
        const float e3 = TR ? __half2float(lph[(size_t)(A3.y & 0xffffu) * Bc + lane])
                            : __expf(lpf[(size_t)lane * Dc + (A3.y & 0xffffu)]);
        const float a0 = __half2float(alpha_old[(size_t)A0.x * Bc + lane]);
        const float a1 = __half2float(alpha_old[(size_t)A1.x * Bc + lane]);
        const float a2 = __half2float(alpha_old[(size_t)A2.x * Bc + lane]);
        const float a3 = __half2float(alpha_old[(size_t)A3.x * Bc + lane]);
        s0 = fmaf(a0 * w0, e0, s0);
        s1 = fmaf(a1 * w1, e1, s1);
        s2 = fmaf(a2 * w2, e2, s2);
        s3 = fmaf(a3 * w3, e3, s3);
    }
    for (; i < hi; ++i) {
        const uint2 A0 = arcs[i];
        const float w0 = __half2float(__ushort_as_half((unsigned short)(A0.y >> 16)));
        const float e0 = TR ? __half2float(lph[(size_t)(A0.y & 0xffffu) * Bc + lane])
                            : __expf(lpf[(size_t)lane * Dc + (A0.y & 0xffffu)]);
        const float a0 = __half2float(alpha_old[(size_t)A0.x * Bc + lane]);
        s0 = fmaf(a0 * w0, e0, s0);
    }
    const float s = (s0 + s1) + (s2 + s3);
    alpha_new[(size_t)wave * Bc + lane] = __float2half(fminf(s * scale, STORE_CAP));
    if (wave == 0) off_new[lane] = off_old[lane] + (__logf(dref) - 5.0f);
}

// ---- final: per-batch logsumexp(log(EA) + final_logp) + OFF[b], atomicAdd ----
__global__ void final_reduce_kernel(const __half* __restrict__ alpha,
                                    const float* __restrict__ off,
                                    const float* __restrict__ final_logp,
                                    float* __restrict__ out, int S) {
    const int b = blockIdx.x;     // 0..B-1
    const int tid = threadIdx.x;  // 256
    float m = NEGV, sum = 0.0f;
    for (int s = tid; s < S; s += 256) {
        float ea = __half2float(alpha[(size_t)s * Bc + b]);
        float v = __logf(ea + 1e-35f) + final_logp[s];
        float nm = fmaxf(m, v);
        sum = sum * __expf(m - nm) + __expf(v - nm);
        m = nm;
    }
    __shared__ float mArr[256], sArr[256];
    mArr[tid] = m; sArr[tid] = sum;
    __syncthreads();
    for (int o = 128; o > 0; o >>= 1) {
        if (tid < o) {
            float m2 = mArr[tid + o], s2 = sArr[tid + o];
            float nm = fmaxf(mArr[tid], m2);
            sArr[tid] = sArr[tid] * __expf(mArr[tid] - nm) + s2 * __expf(m2 - nm);
            mArr[tid] = nm;
        }
        __syncthreads();
    }
    if (tid == 0) {
        float per = fmaxf(mArr[0], NEGV) + logf(sArr[0] + 1e-30f) + off[b];
        atomicAdd(out, per);
    }
}

extern "C" void kernel_launch(void* const* d_in, const int* in_sizes, int n_in,
                              void* d_out, int out_size, void* d_ws, size_t ws_size,
                              hipStream_t stream) {
    const float* input      = (const float*)d_in[0];
    const float* arc_logw   = (const float*)d_in[1];
    const float* init_logp  = (const float*)d_in[2];
    const float* final_logp = (const float*)d_in[3];
    const int*   from_state = (const int*)d_in[4];
    const int*   to_state   = (const int*)d_in[5];
    const int*   pdf_id     = (const int*)d_in[6];
    const int S = in_sizes[2];
    const int A = in_sizes[4];

    char* ws = (char*)d_ws;
    size_t off = 0;
    auto alloc = [&](size_t bytes) -> char* {
        char* p = ws + off;
        off += (bytes + 255) & ~(size_t)255;
        return p;
    };

    const size_t need_small =
        2 * (((size_t)S * Bc * 2 + 255) & ~(size_t)255) +   // alphaA/B fp16
        (((size_t)A * 8 + 255) & ~(size_t)255) +            // packed arcs
        3 * (((size_t)(S + 1) * 4 + 255) & ~(size_t)255) +  // row_ptr/cursor/count
        2 * 256;                                            // offA/B
    const size_t need_T = (size_t)Tc * Dc * Bc * 2 + 256;
    const bool do_transpose = (ws_size >= need_small + need_T);

    __half* logpT = nullptr;
    if (do_transpose) logpT = (__half*)alloc(need_T);
    __half* alphaA = (__half*)alloc((size_t)S * Bc * 2);
    __half* alphaB = (__half*)alloc((size_t)S * Bc * 2);
    float* offA    = (float*)alloc(Bc * 4);
    float* offB    = (float*)alloc(Bc * 4);
    int*   row_ptr = (int*)alloc((size_t)(S + 1) * 4);
    int*   cursor  = (int*)alloc((size_t)(S + 1) * 4);
    int*   count   = (int*)alloc((size_t)(S + 1) * 4);
    uint2* a_pack  = (uint2*)alloc((size_t)A * 8);

    hipMemsetAsync(count, 0, (size_t)S * 4, stream);
    hipMemsetAsync(d_out, 0, sizeof(float), stream);

    if (do_transpose) {
        dim3 tgrid(Dc / 64, Tc);
        transpose_kernel<<<tgrid, 256, 0, stream>>>(input, logpT);
    }
    init_alpha_kernel<<<(S * Bc + 255) / 256, 256, 0, stream>>>(init_logp, alphaA,
                                                                offA, S);
    hist_kernel<<<(A + 255) / 256, 256, 0, stream>>>(to_state, count, A);
    scan_kernel<<<1, 1024, 0, stream>>>(count, row_ptr, cursor, S);
    scatter_kernel<<<(A + 255) / 256, 256, 0, stream>>>(to_state, from_state, pdf_id,
                                                        arc_logw, cursor, a_pack, A);

    __half* curA = alphaA;  __half* nxtA = alphaB;
    float*  curO = offA;    float*  nxtO = offB;
    // 512-thread blocks: 8 states/block -> ~2500 blocks; pad to mult of 8 for
    // the bijective XCD swizzle.
    int step_blocks = (S + 7) / 8;
    step_blocks = (step_blocks + 7) & ~7;          // 2504 for S=20000
    for (int t = 0; t < Tc; ++t) {
        if (do_transpose) {
            step_kernel<true><<<step_blocks, 512, 0, stream>>>(
                curA, nxtA, curO, nxtO, logpT + (size_t)t * Dc * Bc, row_ptr, a_pack, S);
        } else {
            step_kernel<false><<<step_blocks, 512, 0, stream>>>(
                curA, nxtA, curO, nxtO, input + (size_t)t * Bc * Dc, row_ptr, a_pack, S);
        }
        __half* ta = curA; curA = nxtA; nxtA = ta;
        float*  to_ = curO; curO = nxtO; nxtO = to_;
    }
    final_reduce_kernel<<<Bc, 256, 0, stream>>>(curA, curO, final_logp, (float*)d_out, S);
}